// Round 1
// baseline (1308.372 us; speedup 1.0000x reference)
//
#include <hip/hip_runtime.h>
#include <cmath>

// ---------------------------------------------------------------------------
// TimestepVisionTransformer  — fp32 correctness-first implementation.
// B=128, IMG=224, P=16, C_IN=1, E=96, H=4, d=24, NAX=14, N=196, M=B*N=25088
// ---------------------------------------------------------------------------

#define B_   128
#define NPATCH 196
#define M_ROWS (B_*NPATCH)     // 25088
#define E_   96

// ---------------------------------------------------------------------------
// time embedding: 1 block x 128 threads
// ---------------------------------------------------------------------------
__global__ void k_time(const float* __restrict__ ts,
                       const float* __restrict__ Wt1, const float* __restrict__ bt1,
                       const float* __restrict__ Wt2, const float* __restrict__ bt2,
                       float* __restrict__ timev)
{
    __shared__ float h[128];
    float e = 0.69314718055994530942f * ts[0];
    float sv = sinf(e), cv = cosf(e);
    int t = threadIdx.x;
    float z = sv * Wt1[t] + cv * Wt1[128 + t] + bt1[t];
    h[t] = z / (1.f + expf(-z));
    __syncthreads();
    if (t < 96) {
        float acc = bt2[t];
        for (int j = 0; j < 128; ++j) acc += h[j] * Wt2[j * 96 + t];
        timev[t] = acc;
    }
}

// ---------------------------------------------------------------------------
// patch embed GEMM  [25088 x 256] @ WpT[256 x 96]  + bias + RoPE epilogue
// grid 392 blocks, 256 threads; tile 64 patches x 96 ch, K in 4 chunks of 64
// ---------------------------------------------------------------------------
__global__ void __launch_bounds__(256) k_patch(const float* __restrict__ x,
                                               const float* __restrict__ Wp,
                                               const float* __restrict__ bp,
                                               float* __restrict__ out)
{
    __shared__ float As[64][65];
    __shared__ float Ws[64][97];
    int t = threadIdx.x;
    int p0 = blockIdx.x * 64;
    int rg = t >> 4, cg = t & 15;      // rows rg*4.. , cols cg*6..
    float acc[4][6] = {};

    for (int kc = 0; kc < 4; ++kc) {
        __syncthreads();
        // stage A: 64 patches x 64 k (k = py*16+px, py = kc*4 + kl/16)
        for (int idx = t; idx < 64 * 64; idx += 256) {
            int p = idx >> 6, kl = idx & 63;
            int patch = p0 + p;
            int b = patch / NPATCH, n = patch % NPATCH;
            int ny = n / 14, nx = n % 14;
            int py = kc * 4 + (kl >> 4), px = kl & 15;
            As[p][kl] = x[((size_t)b * 224 + ny * 16 + py) * 224 + nx * 16 + px];
        }
        // stage W transposed: Ws[kl][e] = Wp[e*256 + kc*64 + kl]
        for (int idx = t; idx < 64 * 96; idx += 256) {
            int e = idx >> 6, kl = idx & 63;
            Ws[kl][e] = Wp[e * 256 + kc * 64 + kl];
        }
        __syncthreads();
        for (int kk = 0; kk < 64; ++kk) {
            float a0 = As[rg * 4 + 0][kk];
            float a1 = As[rg * 4 + 1][kk];
            float a2 = As[rg * 4 + 2][kk];
            float a3 = As[rg * 4 + 3][kk];
            const float* wrow = &Ws[kk][cg * 6];
            #pragma unroll
            for (int j = 0; j < 6; ++j) {
                float wv = wrow[j];
                acc[0][j] += a0 * wv; acc[1][j] += a1 * wv;
                acc[2][j] += a2 * wv; acc[3][j] += a3 * wv;
            }
        }
    }
    // epilogue: + bias, RoPE pairs (cols cg*6.. are pair-aligned), write [patch][e]
    #pragma unroll
    for (int i = 0; i < 4; ++i) {
        int patch = p0 + rg * 4 + i;
        int n = patch % NPATCH;
        int ny = n / 14, nx = n % 14;
        float yx = (float)(ny + nx);
        #pragma unroll
        for (int j = 0; j < 3; ++j) {
            int e0 = cg * 6 + 2 * j;
            float xe = acc[i][2 * j]     + bp[e0];
            float ye = acc[i][2 * j + 1] + bp[e0 + 1];
            float fi = (float)(e0 >> 1);
            float theta = expf(fi * (-2.f / 96.f) * 9.210340371976184f); // ln(1e4)
            float ang = theta * yx;
            float c = cosf(ang), s = sinf(ang);
            out[(size_t)patch * 96 + e0]     = xe * c - ye * s;
            out[(size_t)patch * 96 + e0 + 1] = xe * s + ye * c;
        }
    }
}

// ---------------------------------------------------------------------------
// row LayerNorm over 96, wave per row
// ---------------------------------------------------------------------------
__global__ void __launch_bounds__(256) k_ln_row(const float* __restrict__ x,
                                                const float* __restrict__ g,
                                                const float* __restrict__ bv,
                                                float* __restrict__ out, int M)
{
    int lane = threadIdx.x & 63;
    int gw = (blockIdx.x * 256 + threadIdx.x) >> 6;
    int nw = (gridDim.x * 256) >> 6;
    float g0 = g[lane], b0 = bv[lane];
    float g1 = 0.f, b1 = 0.f;
    if (lane < 32) { g1 = g[64 + lane]; b1 = bv[64 + lane]; }
    for (int r = gw; r < M; r += nw) {
        const float* xr = x + (size_t)r * 96;
        float a = xr[lane];
        float c = (lane < 32) ? xr[64 + lane] : 0.f;
        float s = a + c, q = a * a + c * c;
        #pragma unroll
        for (int off = 32; off; off >>= 1) {
            s += __shfl_xor(s, off);
            q += __shfl_xor(q, off);
        }
        float mu = s * (1.f / 96.f);
        float rstd = rsqrtf(q * (1.f / 96.f) - mu * mu + 1e-5f);
        float* orow = out + (size_t)r * 96;
        orow[lane] = (a - mu) * rstd * g0 + b0;
        if (lane < 32) orow[64 + lane] = (c - mu) * rstd * g1 + b1;
    }
}

// ---------------------------------------------------------------------------
// generic row GEMM: A[M,96] @ W[96, NCHUNKS*96] + bias, epilogues
// grid M/64 blocks, 256 threads; tile 64 x 96 per chunk
// ---------------------------------------------------------------------------
template<int NCHUNKS, bool SILU, bool RES, bool ADDTIME, bool TRANSW>
__global__ void __launch_bounds__(256) k_gemm96(const float* __restrict__ A,
                                                const float* __restrict__ W,
                                                const float* __restrict__ bias,
                                                const float* __restrict__ res,
                                                const float* __restrict__ timev,
                                                float* __restrict__ out)
{
    __shared__ float As[64][97];
    __shared__ float Ws[96 * 96];
    constexpr int NTOT = NCHUNKS * 96;
    int t = threadIdx.x;
    size_t row0 = (size_t)blockIdx.x * 64;
    for (int idx = t; idx < 64 * 96; idx += 256)
        As[idx / 96][idx % 96] = A[row0 * 96 + idx];
    int rg = t >> 4, cg = t & 15;
    for (int ch = 0; ch < NCHUNKS; ++ch) {
        __syncthreads();
        for (int idx = t; idx < 96 * 96; idx += 256) {
            int k = idx / 96, c = idx % 96;
            Ws[idx] = W[k * NTOT + ch * 96 + c];
        }
        __syncthreads();
        float acc[4][6] = {};
        for (int kk = 0; kk < 96; ++kk) {
            float a0 = As[rg * 4 + 0][kk];
            float a1 = As[rg * 4 + 1][kk];
            float a2 = As[rg * 4 + 2][kk];
            float a3 = As[rg * 4 + 3][kk];
            const float* wrow = &Ws[kk * 96 + cg * 6];
            #pragma unroll
            for (int j = 0; j < 6; ++j) {
                float wv = wrow[j];
                acc[0][j] += a0 * wv; acc[1][j] += a1 * wv;
                acc[2][j] += a2 * wv; acc[3][j] += a3 * wv;
            }
        }
        #pragma unroll
        for (int i = 0; i < 4; ++i) {
            size_t row = row0 + rg * 4 + i;
            #pragma unroll
            for (int j = 0; j < 6; ++j) {
                int lc = cg * 6 + j;
                int col = ch * 96 + lc;
                float v = acc[i][j] + bias[col];
                if constexpr (RES)     v += res[row * 96 + lc];
                if constexpr (ADDTIME) v += timev[lc];
                if constexpr (SILU)    v = v / (1.f + expf(-v));
                if constexpr (TRANSW) {
                    size_t b = row / NPATCH; int n = (int)(row % NPATCH);
                    out[(b * 96 + col) * NPATCH + n] = v;
                } else {
                    out[row * NTOT + col] = v;
                }
            }
        }
    }
}

// ---------------------------------------------------------------------------
// attention: grid B*H blocks, 256 threads (4 waves); K,V in LDS (pad 25)
// ---------------------------------------------------------------------------
__global__ void __launch_bounds__(256) k_attn(const float* __restrict__ qkv,
                                              float* __restrict__ o)
{
    int bh = blockIdx.x;
    int b = bh >> 2, h = bh & 3;
    __shared__ float K[196][25];
    __shared__ float V[196][25];
    __shared__ float P[4][200];
    const float* base = qkv + (size_t)b * NPATCH * 288;
    int t = threadIdx.x;
    for (int idx = t; idx < 196 * 24; idx += 256) {
        int n = idx / 24, d = idx % 24;
        K[n][d] = base[n * 288 + 96  + h * 24 + d];
        V[n][d] = base[n * 288 + 192 + h * 24 + d];
    }
    __syncthreads();
    int wave = t >> 6, lane = t & 63;
    const float scale = 0.2041241452319315f;   // 1/sqrt(24)
    for (int q = wave; q < 196; q += 4) {
        float qv[24];
        const float* qrow = base + q * 288 + h * 24;
        #pragma unroll
        for (int d = 0; d < 24; ++d) qv[d] = qrow[d];
        float sc[4];
        float smax = -INFINITY;
        #pragma unroll
        for (int c = 0; c < 4; ++c) {
            int k = c * 64 + lane;
            float s = -INFINITY;
            if (k < 196) {
                float a = 0.f;
                #pragma unroll
                for (int d = 0; d < 24; ++d) a += qv[d] * K[k][d];
                s = a * scale;
            }
            sc[c] = s;
            smax = fmaxf(smax, s);
        }
        #pragma unroll
        for (int off = 32; off; off >>= 1) smax = fmaxf(smax, __shfl_xor(smax, off));
        float sum = 0.f;
        #pragma unroll
        for (int c = 0; c < 4; ++c) {
            int k = c * 64 + lane;
            float e = expf(sc[c] - smax);      // -inf -> 0
            if (k < 196) { P[wave][k] = e; sum += e; }
        }
        #pragma unroll
        for (int off = 32; off; off >>= 1) sum += __shfl_xor(sum, off);
        float inv = 1.f / sum;
        // AV: lanes 0..47 split keys in two halves of 98
        float accv = 0.f;
        if (lane < 48) {
            int dd = lane % 24;
            int k0 = (lane / 24) * 98;
            for (int k = k0; k < k0 + 98; ++k) accv += P[wave][k] * V[k][dd];
        }
        float other = __shfl(accv, lane + 24, 64);
        if (lane < 24)
            o[((size_t)b * NPATCH + q) * 96 + h * 24 + lane] = (accv + other) * inv;
    }
}

// ---------------------------------------------------------------------------
// transposed conv (stride 2, k=4, pad 2) as 4 parity classes, 2x2 taps each.
// grid: B * (COUT/G) * S blocks, 256 threads; per-parity float4 weights in LDS
// out[b][o][HOUT*HOUT] = conv + bias   (no activation here)
// ---------------------------------------------------------------------------
template<int CIN, int HIN, int COUT, int G, int S>
__global__ void __launch_bounds__(256) k_convt(const float* __restrict__ x,
                                               const float* __restrict__ w,
                                               const float* __restrict__ bias,
                                               float* __restrict__ out)
{
    constexpr int HOUT = 2 * HIN;
    constexpr int NPIX = HOUT * HOUT;
    constexpr int PIXPB = NPIX / S;
    int bid = blockIdx.x;
    int s  = bid % S;
    int og = (bid / S) % (COUT / G);
    int b  = bid / (S * (COUT / G));
    int o0 = og * G;
    __shared__ __align__(16) float wp[4 * CIN * G * 4];
    int t = threadIdx.x;
    for (int i = t; i < 4 * CIN * G * 4; i += 256) {
        int j   = i & 3;
        int par = i / (CIN * G * 4);
        int rem = i % (CIN * G * 4);
        int ci  = rem / (G * 4);
        int oo  = (rem >> 2) % G;
        int ry = par >> 1, rx = par & 1;
        int wy = (j < 2)  ? (3 - ry) : (1 - ry);
        int wx = (j & 1)  ? (1 - rx) : (3 - rx);
        wp[i] = w[((size_t)ci * COUT + (o0 + oo)) * 16 + wy * 4 + wx];
    }
    __syncthreads();
    const float* xb = x + (size_t)b * CIN * HIN * HIN;
    float* ob = out + (size_t)b * COUT * NPIX;
    int pix0 = s * PIXPB;
    for (int pp = t; pp < PIXPB; pp += 256) {
        int idx = pix0 + pp;
        int oy = idx / HOUT, ox = idx % HOUT;
        int ry = oy & 1, rx = ox & 1;
        int iy0 = ((oy + ry) >> 1) - 1;
        int ix0 = ((ox + rx) >> 1) - 1;
        int iy1 = iy0 + 1, ix1 = ix0 + 1;
        bool y0 = iy0 >= 0, y1 = iy1 < HIN, x0 = ix0 >= 0, x1 = ix1 < HIN;
        const float4* wpar = (const float4*)(wp) + (size_t)(ry * 2 + rx) * CIN * G;
        float acc[G];
        #pragma unroll
        for (int g_ = 0; g_ < G; ++g_) acc[g_] = 0.f;
        for (int ci = 0; ci < CIN; ++ci) {
            const float* xc = xb + (size_t)ci * HIN * HIN;
            float v00 = (y0 && x0) ? xc[iy0 * HIN + ix0] : 0.f;
            float v01 = (y0 && x1) ? xc[iy0 * HIN + ix1] : 0.f;
            float v10 = (y1 && x0) ? xc[iy1 * HIN + ix0] : 0.f;
            float v11 = (y1 && x1) ? xc[iy1 * HIN + ix1] : 0.f;
            const float4* wci = wpar + ci * G;
            #pragma unroll
            for (int g_ = 0; g_ < G; ++g_) {
                float4 wv = wci[g_];
                acc[g_] += v00 * wv.x + v01 * wv.y + v10 * wv.z + v11 * wv.w;
            }
        }
        #pragma unroll
        for (int g_ = 0; g_ < G; ++g_)
            ob[(size_t)(o0 + g_) * NPIX + idx] = acc[g_] + bias[o0 + g_];
    }
}

// ---------------------------------------------------------------------------
// in-place spatial LayerNorm (per b,o over HW) + per-position affine + silu
// grid: B*COUT blocks
// ---------------------------------------------------------------------------
template<int HW>
__global__ void __launch_bounds__(256) k_ln_spatial(float* __restrict__ f,
                                                    const float* __restrict__ g,
                                                    const float* __restrict__ bv)
{
    size_t base = (size_t)blockIdx.x * HW;
    int t = threadIdx.x;
    float s = 0.f, q = 0.f;
    for (int i = t; i < HW; i += 256) {
        float v = f[base + i];
        s += v; q += v * v;
    }
    #pragma unroll
    for (int off = 32; off; off >>= 1) {
        s += __shfl_xor(s, off);
        q += __shfl_xor(q, off);
    }
    __shared__ float rs[8];
    int wave = t >> 6, lane = t & 63;
    if (lane == 0) { rs[wave] = s; rs[4 + wave] = q; }
    __syncthreads();
    float st = rs[0] + rs[1] + rs[2] + rs[3];
    float qt = rs[4] + rs[5] + rs[6] + rs[7];
    float mu = st / (float)HW;
    float rstd = rsqrtf(qt / (float)HW - mu * mu + 1e-5f);
    for (int i = t; i < HW; i += 256) {
        float v = (f[base + i] - mu) * rstd * g[i] + bv[i];
        f[base + i] = v / (1.f + expf(-v));
    }
}

// ---------------------------------------------------------------------------
// final convT (12 -> 1, 112 -> 224) + silu + clip, write d_out
// grid: B*224*224/256 = 25088 blocks
// ---------------------------------------------------------------------------
__global__ void __launch_bounds__(256) k_convt4(const float* __restrict__ x,
                                                const float* __restrict__ w,
                                                const float* __restrict__ bias,
                                                float* __restrict__ out)
{
    __shared__ __align__(16) float wp[4 * 12 * 4];
    int t = threadIdx.x;
    if (t < 192) {
        int j = t & 3, ci = (t >> 2) % 12, par = t / 48;
        int ry = par >> 1, rx = par & 1;
        int wy = (j < 2) ? (3 - ry) : (1 - ry);
        int wx = (j & 1) ? (1 - rx) : (3 - rx);
        wp[t] = w[ci * 16 + wy * 4 + wx];
    }
    __syncthreads();
    float b0 = bias[0];
    size_t idx = (size_t)blockIdx.x * 256 + t;
    int b = (int)(idx / (224 * 224));
    int r = (int)(idx % (224 * 224));
    int oy = r / 224, ox = r % 224;
    int ry = oy & 1, rx = ox & 1;
    int iy0 = ((oy + ry) >> 1) - 1, ix0 = ((ox + rx) >> 1) - 1;
    int iy1 = iy0 + 1, ix1 = ix0 + 1;
    bool y0 = iy0 >= 0, y1 = iy1 < 112, x0 = ix0 >= 0, x1 = ix1 < 112;
    const float4* wpar = (const float4*)(wp) + (ry * 2 + rx) * 12;
    const float* xb = x + (size_t)b * 12 * 112 * 112;
    float acc = b0;
    #pragma unroll 4
    for (int ci = 0; ci < 12; ++ci) {
        const float* xc = xb + ci * 12544;
        float v00 = (y0 && x0) ? xc[iy0 * 112 + ix0] : 0.f;
        float v01 = (y0 && x1) ? xc[iy0 * 112 + ix1] : 0.f;
        float v10 = (y1 && x0) ? xc[iy1 * 112 + ix0] : 0.f;
        float v11 = (y1 && x1) ? xc[iy1 * 112 + ix1] : 0.f;
        float4 wv = wpar[ci];
        acc += v00 * wv.x + v01 * wv.y + v10 * wv.z + v11 * wv.w;
    }
    float v = acc / (1.f + expf(-acc));
    out[idx] = fminf(fmaxf(v, 0.f), 1.f);
}

// ---------------------------------------------------------------------------
// launch
// ---------------------------------------------------------------------------
extern "C" void kernel_launch(void* const* d_in, const int* in_sizes, int n_in,
                              void* d_out, int out_size, void* d_ws, size_t ws_size,
                              hipStream_t stream)
{
    const float* x       = (const float*)d_in[0];
    const float* ts      = (const float*)d_in[1];
    const float* Wp      = (const float*)d_in[2];
    const float* bp      = (const float*)d_in[3];
    const float* Wt1     = (const float*)d_in[4];
    const float* bt1     = (const float*)d_in[5];
    const float* Wt2     = (const float*)d_in[6];
    const float* bt2     = (const float*)d_in[7];
    const float* a0_g    = (const float*)d_in[8];
    const float* a0_b    = (const float*)d_in[9];
    const float* a0_Wqkv = (const float*)d_in[10];
    const float* a0_bqkv = (const float*)d_in[11];
    const float* a0_Wo   = (const float*)d_in[12];
    const float* a0_bo   = (const float*)d_in[13];
    const float* a1_g    = (const float*)d_in[14];
    const float* a1_b    = (const float*)d_in[15];
    const float* a1_Wqkv = (const float*)d_in[16];
    const float* a1_bqkv = (const float*)d_in[17];
    const float* a1_Wo   = (const float*)d_in[18];
    const float* a1_bo   = (const float*)d_in[19];
    const float* Wm0     = (const float*)d_in[20];
    const float* bm0     = (const float*)d_in[21];
    const float* Wm1     = (const float*)d_in[22];
    const float* bm1     = (const float*)d_in[23];
    const float* Wm2     = (const float*)d_in[24];
    const float* bm2     = (const float*)d_in[25];
    const float* Wd1     = (const float*)d_in[26];
    const float* bd1     = (const float*)d_in[27];
    const float* l1g     = (const float*)d_in[28];
    const float* l1b     = (const float*)d_in[29];
    const float* Wd2     = (const float*)d_in[30];
    const float* bd2     = (const float*)d_in[31];
    const float* l2g     = (const float*)d_in[32];
    const float* l2b     = (const float*)d_in[33];
    const float* Wd3     = (const float*)d_in[34];
    const float* bd3     = (const float*)d_in[35];
    const float* l3g     = (const float*)d_in[36];
    const float* l3b     = (const float*)d_in[37];
    const float* Wd4     = (const float*)d_in[38];
    const float* bd4     = (const float*)d_in[39];
    float* out = (float*)d_out;

    // workspace arena (floats); R = 25088*96
    const size_t R = 2408448;
    const size_t NEED = (512 + 14 * R) * sizeof(float);   // ~134.9 MB
    if (ws_size < NEED) return;  // loud failure rather than corruption
    float* ws   = (float*)d_ws;
    float* tvec = ws;                  // 96
    float* p0   = ws + 512;            // R
    float* h    = ws + 512 + R;        // R
    float* qkvb = ws + 512 + 2 * R;    // 3R
    float* ob   = ws + 512 + 5 * R;    // R
    float* p1   = ws + 512 + 6 * R;    // R
    float* f0   = ob;                  // R      (o free when MLP3 writes)
    float* f1   = ws + 512;            // 2R     (p0+h regions, free after MLP3)
    float* f2   = ws + 512 + 2 * R;    // 4R     (qkv+o regions)
    float* f3   = ws + 512 + 6 * R;    // 8R     (p1 + tail)

    k_time<<<1, 128, 0, stream>>>(ts, Wt1, bt1, Wt2, bt2, tvec);
    k_patch<<<M_ROWS / 64, 256, 0, stream>>>(x, Wp, bp, p0);

    // MHSA block 0
    k_ln_row<<<1024, 256, 0, stream>>>(p0, a0_g, a0_b, h, M_ROWS);
    k_gemm96<3, false, false, false, false><<<M_ROWS / 64, 256, 0, stream>>>(
        h, a0_Wqkv, a0_bqkv, nullptr, nullptr, qkvb);
    k_attn<<<B_ * 4, 256, 0, stream>>>(qkvb, ob);
    k_gemm96<1, false, true, false, false><<<M_ROWS / 64, 256, 0, stream>>>(
        ob, a0_Wo, a0_bo, p0, nullptr, p1);

    // MHSA block 1 (+time in epilogue)
    k_ln_row<<<1024, 256, 0, stream>>>(p1, a1_g, a1_b, h, M_ROWS);
    k_gemm96<3, false, false, false, false><<<M_ROWS / 64, 256, 0, stream>>>(
        h, a1_Wqkv, a1_bqkv, nullptr, nullptr, qkvb);
    k_attn<<<B_ * 4, 256, 0, stream>>>(qkvb, ob);
    k_gemm96<1, false, true, true, false><<<M_ROWS / 64, 256, 0, stream>>>(
        ob, a1_Wo, a1_bo, p1, tvec, p0);

    // MLP x3 (silu); last writes channel-major f0[b][e][n]
    k_gemm96<1, true, false, false, false><<<M_ROWS / 64, 256, 0, stream>>>(
        p0, Wm0, bm0, nullptr, nullptr, p1);
    k_gemm96<1, true, false, false, false><<<M_ROWS / 64, 256, 0, stream>>>(
        p1, Wm1, bm1, nullptr, nullptr, p0);
    k_gemm96<1, true, false, false, true><<<M_ROWS / 64, 256, 0, stream>>>(
        p0, Wm2, bm2, nullptr, nullptr, f0);

    // decoder
    k_convt<96, 14, 48, 8, 1><<<B_ * 6, 256, 0, stream>>>(f0, Wd1, bd1, f1);
    k_ln_spatial<784><<<B_ * 48, 256, 0, stream>>>(f1, l1g, l1b);
    k_convt<48, 28, 24, 6, 1><<<B_ * 4, 256, 0, stream>>>(f1, Wd2, bd2, f2);
    k_ln_spatial<3136><<<B_ * 24, 256, 0, stream>>>(f2, l2g, l2b);
    k_convt<24, 56, 12, 12, 4><<<B_ * 4, 256, 0, stream>>>(f2, Wd3, bd3, f3);
    k_ln_spatial<12544><<<B_ * 12, 256, 0, stream>>>(f3, l3g, l3b);
    k_convt4<<<(B_ * 224 * 224) / 256, 256, 0, stream>>>(f3, Wd4, bd4, out);
}